// Round 3
// baseline (5893.620 us; speedup 1.0000x reference)
//
#include <hip/hip_runtime.h>
#include <math.h>

#define P    256
#define PM1  255
#define KB   16

// ============================================================================
// K_t: transpose A1, A2 (256x256) into ws (coalesced weight-column reads).
// ============================================================================
__global__ void __launch_bounds__(256) k_transpose(
    const float* __restrict__ A1, const float* __restrict__ A2,
    float* __restrict__ A1T, float* __restrict__ A2T) {
  __shared__ float tile[64][65];
  const int bid = blockIdx.x;
  const float* src = (bid < 16) ? A1 : A2;
  float* dst       = (bid < 16) ? A1T : A2T;
  const int tl = bid & 15;
  const int R0 = (tl >> 2) << 6;
  const int C0 = (tl & 3) << 6;
  const int tx = threadIdx.x & 63;
  const int ty = threadIdx.x >> 6;
#pragma unroll
  for (int k = 0; k < 16; k++) {
    const int r = (k << 2) + ty;
    tile[r][tx] = src[(R0 + r) * P + C0 + tx];
  }
  __syncthreads();
#pragma unroll
  for (int k = 0; k < 16; k++) {
    const int c = (k << 2) + ty;
    dst[(C0 + c) * P + R0 + tx] = tile[tx][c];
  }
}

// ============================================================================
// K_wct: WcT[j][e] = Wc[e][j], zero-padded to 256x256 (255-space transpose).
// ============================================================================
__global__ void __launch_bounds__(256) k_wct(
    const float* __restrict__ Wc, float* __restrict__ WcT) {
  const int j = blockIdx.x;
  const int e = threadIdx.x;
  WcT[j * P + e] = (j < PM1 && e < PM1) ? Wc[e * PM1 + j] : 0.f;
}

// ============================================================================
// K1: pass 1, BLOCKED (KB=16 columns per block).
// Wc (zero-padded, compressed 255-space) register-resident as in prior rounds.
// Per block:
//   load  : T_blk[k][e] = current ThB row (c0+k), compressed for col c0+k.
//           (rows < c0 are final, in-block rows original -> exactly the mix
//            the deferred formulation needs); Wcc[k] = Wc column c0+k.
//   phase A: Y[k] = Wc @ T_blk[k] for all 16 k at once (batched matvec,
//            partial per 64-col wave slice -> one LDS reduce round).
//   phase B: per column (2 tiny barriers): finalize y=(Y[k]+bc)*scale, write
//            global col+row, then propagate to future in-block columns:
//            Y[kp] += Wcc[k] * (final - orig), NO dot products needed.
// ============================================================================
__global__ void __launch_bounds__(512, 1) k_pass1(
    float* __restrict__ Th,                  // d_out, B x P x P, in-place
    const float* __restrict__ Wc,            // 255 x 255
    const float* __restrict__ bc,            // 255
    const float* __restrict__ WcT) {         // 256 x 256 zero-padded transpose
  const int b    = blockIdx.x;
  const int tid  = threadIdx.x;
  const int lane = tid & 63;
  const int wid  = tid >> 6;
  const int wrr  = wid >> 2;
  const int wcb  = wid & 3;
  const int r0   = (wrr << 7) + lane;
  const int r1   = r0 + 64;
  const int cbase = wcb << 6;

  float w0[64], w1[64];
#pragma unroll
  for (int k = 0; k < 64; k++) {
    const int c = cbase + k;
    w0[k] = (r0 < PM1 && c < PM1) ? Wc[r0 * PM1 + c] : 0.f;
    w1[k] = (r1 < PM1 && c < PM1) ? Wc[r1 * PM1 + c] : 0.f;
  }

  extern __shared__ float smem[];
  float (*T)[260]   = (float (*)[260])(smem);             // 16 x 260
  float (*Y)[260]   = (float (*)[260])(smem + 16 * 260);  // 16 x 260
  float (*Wcc)[260] = (float (*)[260])(smem + 32 * 260);  // 16 x 260
  float* partp      = smem + 48 * 260;                    // [4][256][17]
  __shared__ float bcl[256];
  if (tid < 256) bcl[tid] = (tid < PM1) ? bc[tid] : 0.f;

  float* __restrict__ ThB = Th + (size_t)b * P * P;

  for (int blk = 0; blk < 16; blk++) {
    const int c0 = blk << 4;
    __syncthreads();   // prev block done; prior global writes drained
    // ---- loads: T_blk (current mixed state) + Wc columns ----
#pragma unroll
    for (int q = 0; q < 8; q++) {
      const int idx = (q << 9) + tid;
      const int k = idx >> 8, e = idx & 255;
      const int row = c0 + k;
      T[k][e]   = (e < PM1) ? ThB[row * P + e + (e >= row ? 1 : 0)] : 0.f;
      Wcc[k][e] = WcT[row * P + e];
    }
    __syncthreads();
    // ---- phase A: partial matvecs (wave-uniform float4 broadcasts) ----
    float acc0[KB], acc1[KB];
#pragma unroll
    for (int kb = 0; kb < KB; kb++) {
      const float4* tb = (const float4*)&T[kb][cbase];
      float a0 = 0.f, a1 = 0.f;
#pragma unroll
      for (int i = 0; i < 16; i++) {
        const float4 t4 = tb[i];
        a0 = fmaf(w0[4*i+0], t4.x, a0); a0 = fmaf(w0[4*i+1], t4.y, a0);
        a0 = fmaf(w0[4*i+2], t4.z, a0); a0 = fmaf(w0[4*i+3], t4.w, a0);
        a1 = fmaf(w1[4*i+0], t4.x, a1); a1 = fmaf(w1[4*i+1], t4.y, a1);
        a1 = fmaf(w1[4*i+2], t4.z, a1); a1 = fmaf(w1[4*i+3], t4.w, a1);
      }
      acc0[kb] = a0; acc1[kb] = a1;
    }
    {
      float* p0 = &partp[(wcb * 256 + r0) * 17];
      float* p1 = &partp[(wcb * 256 + r1) * 17];
#pragma unroll
      for (int kb = 0; kb < KB; kb++) { p0[kb] = acc0[kb]; p1[kb] = acc1[kb]; }
    }
    __syncthreads();
    // ---- reduce 4 wave-groups into Y ----
    {
      const int e = tid & 255;
      const int kb0 = (tid >> 8) << 3;
#pragma unroll
      for (int q = 0; q < 8; q++) {
        const int kb = kb0 + q;
        Y[kb][e] = partp[(0*256+e)*17+kb] + partp[(1*256+e)*17+kb]
                 + partp[(2*256+e)*17+kb] + partp[(3*256+e)*17+kb];
      }
    }
    // ---- phase B: 16 sequential columns, tiny work ----
    for (int k = 0; k < KB; k++) {
      const int col = c0 + k;
      __syncthreads();                       // Y[k] final (reduce or props)
      if (tid < PM1) {
        const float yf = (Y[k][tid] + bcl[tid]) * 0.0625f;  // 1/sqrt(256)
        const int iout = tid + (tid >= col ? 1 : 0);
        ThB[iout * P + col] = yf;
        ThB[col * P + iout] = yf;
        Y[k][tid] = yf;
      }
      __syncthreads();                       // yf visible in LDS
      if (k < KB - 1) {
        const int e  = tid & 255;
        const int hh = tid >> 8;
        const float wce = Wcc[k][e];
        for (int kp = k + 1 + hh; kp < KB; kp += 2) {
          const float d = Y[k][c0 + kp - 1] - T[k][c0 + kp - 1];
          Y[kp][e] = fmaf(wce, d, Y[kp][e]);
        }
      }
    }
  }
}

// ============================================================================
// K2: MLP for ALL (b,col) pairs (unchanged from round 2 — passed).
// ============================================================================
__global__ void __launch_bounds__(256, 4) k_mlp(
    const float* __restrict__ Th,
    const float* __restrict__ A1T, const float* __restrict__ b1,
    const float* __restrict__ A2T, const float* __restrict__ b2,
    const float* __restrict__ A3,  const float* __restrict__ b3,
    float* __restrict__ gy) {
  const int m0 = blockIdx.x << 4;
  const int b  = m0 >> 8;
  const int c0 = m0 & (P - 1);
  const int t  = threadIdx.x;

  __shared__ __align__(16) float fbuf[16][260];
  __shared__ __align__(16) float hbuf[16][260];
  __shared__ float A3_lds[P];
  if (t < P) A3_lds[t] = A3[t];

  const float* __restrict__ ThB = Th + (size_t)b * P * P;

  {
    const int cc = t & 15;
    const int dr = t >> 4;
    const int c  = c0 + cc;
#pragma unroll
    for (int ii = 0; ii < 16; ii++) {
      const int i = (ii << 4) + dr;
      const float v = ThB[i * P + c];
      const int pos = (i == c) ? 0 : (i < c ? i + 1 : i);
      fbuf[cc][pos] = v;
    }
  }
  __syncthreads();

  {
    float acc[16];
    const float bv = b1[t];
#pragma unroll
    for (int r = 0; r < 16; r++) acc[r] = bv;
    for (int j4 = 0; j4 < 64; j4++) {
      const int j = j4 << 2;
      const float a0 = A1T[(j + 0) * P + t];
      const float a1 = A1T[(j + 1) * P + t];
      const float a2 = A1T[(j + 2) * P + t];
      const float a3 = A1T[(j + 3) * P + t];
#pragma unroll
      for (int r = 0; r < 16; r++) {
        const float4 f4 = *(const float4*)&fbuf[r][j];
        acc[r] = fmaf(f4.x, a0, acc[r]);
        acc[r] = fmaf(f4.y, a1, acc[r]);
        acc[r] = fmaf(f4.z, a2, acc[r]);
        acc[r] = fmaf(f4.w, a3, acc[r]);
      }
    }
#pragma unroll
    for (int r = 0; r < 16; r++) hbuf[r][t] = fmaxf(acc[r], 0.f);
  }
  __syncthreads();

  {
    float acc[16];
    const float bv = b2[t];
#pragma unroll
    for (int r = 0; r < 16; r++) acc[r] = bv;
    for (int j4 = 0; j4 < 64; j4++) {
      const int j = j4 << 2;
      const float a0 = A2T[(j + 0) * P + t];
      const float a1 = A2T[(j + 1) * P + t];
      const float a2 = A2T[(j + 2) * P + t];
      const float a3 = A2T[(j + 3) * P + t];
#pragma unroll
      for (int r = 0; r < 16; r++) {
        const float4 f4 = *(const float4*)&hbuf[r][j];
        acc[r] = fmaf(f4.x, a0, acc[r]);
        acc[r] = fmaf(f4.y, a1, acc[r]);
        acc[r] = fmaf(f4.z, a2, acc[r]);
        acc[r] = fmaf(f4.w, a3, acc[r]);
      }
    }
    __syncthreads();
#pragma unroll
    for (int r = 0; r < 16; r++) fbuf[r][t] = fmaxf(acc[r], 0.f);
  }
  __syncthreads();

  {
    const int r = t >> 4, sub = t & 15;
    float pq = 0.f;
#pragma unroll
    for (int jj = 0; jj < 16; jj++) {
      const int j = (jj << 4) + sub;
      pq = fmaf(fbuf[r][j], A3_lds[j], pq);
    }
    pq += __shfl_xor(pq, 1);
    pq += __shfl_xor(pq, 2);
    pq += __shfl_xor(pq, 4);
    pq += __shfl_xor(pq, 8);
    if (sub == 0) gy[m0 + r] = expf(pq + b3[0]);
  }
}

// ============================================================================
// K3: pass 2, BLOCKED (KB=16). W (256x256) register-resident; deferred
// rank-1 updates:  W_cur = W_base + sum_j c_j u_j u_j^T  within a block.
//   a(col) = A[k] and y(col) = Y[k] maintained incrementally in LDS.
// Per block:
//   load   : T_blk (post-pass1 Theta rows, static in pass 2; diag zeroed), gys
//   extract: A[k] = W_base row c0+k (symmetry => column)
//   phase A: Y[k] = W_base @ T[k], batched, one reduce round
//   phase B: per column (4 tiny barriers):
//     at = a.t, ty = t.y (wave0 dual half-wave dot)
//     s = at/w22; z = -(y - s a), z[col]=1; diag = gy + ty - s*at
//     propagate to future cols: da/dz dots (16-thread groups) then
//     A[kp] += ca*a[col_kp]*a + cz*z[col_kp]*z ; Y[kp] += ca*da*a + cz*dz*z
//   phase C: W_base += sum_k ca_k a_k a_k^T + cz_k z_k z_k^T  (batched)
// ============================================================================
__global__ void __launch_bounds__(512, 1) k_pass2(
    float* __restrict__ Th,                  // d_out (Theta after pass1)
    const float* __restrict__ Winit,         // B x P x P
    const float* __restrict__ gy) {          // B*P
  const int b    = blockIdx.x;
  const int tid  = threadIdx.x;
  const int lane = tid & 63;
  const int wid  = tid >> 6;
  const int wrr  = wid >> 2;
  const int wcb  = wid & 3;
  const int r0   = (wrr << 7) + lane;
  const int r1   = r0 + 64;
  const int cbase = wcb << 6;

  float w0[64], w1[64];
  const float* __restrict__ WB = Winit + (size_t)b * P * P;
#pragma unroll
  for (int k4 = 0; k4 < 16; k4++) {
    const float4 v0 = *(const float4*)&WB[r0 * P + cbase + (k4 << 2)];
    const float4 v1 = *(const float4*)&WB[r1 * P + cbase + (k4 << 2)];
    w0[(k4 << 2) + 0] = v0.x; w0[(k4 << 2) + 1] = v0.y;
    w0[(k4 << 2) + 2] = v0.z; w0[(k4 << 2) + 3] = v0.w;
    w1[(k4 << 2) + 0] = v1.x; w1[(k4 << 2) + 1] = v1.y;
    w1[(k4 << 2) + 2] = v1.z; w1[(k4 << 2) + 3] = v1.w;
  }

  float* __restrict__ ThB = Th + (size_t)b * P * P;
  const float* __restrict__ gyB = gy + b * P;

  extern __shared__ float smem[];
  float (*T)[260] = (float (*)[260])(smem);               // 16 x 260
  float (*Y)[260] = (float (*)[260])(smem + 16 * 260);    // 16 x 260
  float (*A)[260] = (float (*)[260])(smem + 32 * 260);    // 16 x 260
  float (*Z)[260] = (float (*)[260])(smem + 48 * 260);    // 16 x 260
  float* partp    = smem + 64 * 260;                      // [4][256][17]
  __shared__ float dred[32];
  __shared__ float gys[KB], cas[KB], czs[KB], scw[2];

  for (int blk = 0; blk < 16; blk++) {
    const int c0 = blk << 4;
    __syncthreads();   // prev block's phase C (reads A/Z) done before overwrite
    // ---- loads: T rows (diag zeroed) + gy scalars ----
#pragma unroll
    for (int q = 0; q < 8; q++) {
      const int idx = (q << 9) + tid;
      const int k = idx >> 8, e = idx & 255;
      T[k][e] = (e == c0 + k) ? 0.f : ThB[(c0 + k) * P + e];
    }
    if (tid < KB) gys[tid] = gyB[c0 + tid];
    // ---- extract A[k] = W_base row c0+k (one 16-row window per quarter) ----
    if (r0 >= c0 && r0 < c0 + KB) {
      float4* dst = (float4*)&A[r0 - c0][cbase];
#pragma unroll
      for (int k4 = 0; k4 < 16; k4++)
        dst[k4] = make_float4(w0[(k4 << 2) + 0], w0[(k4 << 2) + 1],
                              w0[(k4 << 2) + 2], w0[(k4 << 2) + 3]);
    }
    if (r1 >= c0 && r1 < c0 + KB) {
      float4* dst = (float4*)&A[r1 - c0][cbase];
#pragma unroll
      for (int k4 = 0; k4 < 16; k4++)
        dst[k4] = make_float4(w1[(k4 << 2) + 0], w1[(k4 << 2) + 1],
                              w1[(k4 << 2) + 2], w1[(k4 << 2) + 3]);
    }
    __syncthreads();   // T ready for phase A (A-extract also done)
    // ---- phase A: partial batched matvecs ----
    float acc0[KB], acc1[KB];
#pragma unroll
    for (int kb = 0; kb < KB; kb++) {
      const float4* tb = (const float4*)&T[kb][cbase];
      float a0 = 0.f, a1 = 0.f;
#pragma unroll
      for (int i = 0; i < 16; i++) {
        const float4 t4 = tb[i];
        a0 = fmaf(w0[4*i+0], t4.x, a0); a0 = fmaf(w0[4*i+1], t4.y, a0);
        a0 = fmaf(w0[4*i+2], t4.z, a0); a0 = fmaf(w0[4*i+3], t4.w, a0);
        a1 = fmaf(w1[4*i+0], t4.x, a1); a1 = fmaf(w1[4*i+1], t4.y, a1);
        a1 = fmaf(w1[4*i+2], t4.z, a1); a1 = fmaf(w1[4*i+3], t4.w, a1);
      }
      acc0[kb] = a0; acc1[kb] = a1;
    }
    {
      float* p0 = &partp[(wcb * 256 + r0) * 17];
      float* p1 = &partp[(wcb * 256 + r1) * 17];
#pragma unroll
      for (int kb = 0; kb < KB; kb++) { p0[kb] = acc0[kb]; p1[kb] = acc1[kb]; }
    }
    __syncthreads();
    {
      const int e = tid & 255;
      const int kb0 = (tid >> 8) << 3;
#pragma unroll
      for (int q = 0; q < 8; q++) {
        const int kb = kb0 + q;
        Y[kb][e] = partp[(0*256+e)*17+kb] + partp[(1*256+e)*17+kb]
                 + partp[(2*256+e)*17+kb] + partp[(3*256+e)*17+kb];
      }
    }
    // ---- phase B: 16 sequential columns ----
    for (int k = 0; k < KB; k++) {
      const int col = c0 + k;
      __syncthreads();                       // A[k]/Y[k] final
      // dots at (lanes 0-31) and ty (lanes 32-63) on wave 0
      if (wid == 0) {
        const int hf = lane >> 5, li = lane & 31, e0 = li << 3;
        const float* va = hf ? &Y[k][0] : &A[k][0];
        const float4 x0 = *(const float4*)&va[e0];
        const float4 x1 = *(const float4*)&va[e0 + 4];
        const float4 y0 = *(const float4*)&T[k][e0];
        const float4 y1 = *(const float4*)&T[k][e0 + 4];
        float sm = x0.x*y0.x + x0.y*y0.y + x0.z*y0.z + x0.w*y0.w
                 + x1.x*y1.x + x1.y*y1.y + x1.z*y1.z + x1.w*y1.w;
        sm += __shfl_xor(sm, 1);  sm += __shfl_xor(sm, 2);
        sm += __shfl_xor(sm, 4);  sm += __shfl_xor(sm, 8);
        sm += __shfl_xor(sm, 16);
        if (li == 0) scw[hf] = sm;
      }
      __syncthreads();                       // B1
      const float at  = scw[0], ty = scw[1];
      const float w22 = A[k][col];
      const float gyv = gys[k];
      const float s   = at / w22;
      if (tid < 256) {
        const float zv = (tid == col) ? 1.f : -(Y[k][tid] - s * A[k][tid]);
        Z[k][tid] = zv;
      } else if (tid == 256) {
        ThB[col * P + col] = gyv + (ty - s * at);
        cas[k] = -1.f / w22;
        czs[k] = 1.f / gyv;
      }
      __syncthreads();                       // B2 (Z, cas/czs ready)
      if (k < KB - 1) {
        const int m2 = (KB - 1 - k) << 1;
        const int g = tid >> 4, gi = tid & 15;
        if (g < m2) {
          const int kp = k + 1 + (g >> 1);
          const float* u  = (g & 1) ? &Z[k][0] : &A[k][0];
          const float* tt = &T[kp][0];
          float sm = 0.f;
#pragma unroll
          for (int j = 0; j < 16; j++) sm = fmaf(u[gi + (j << 4)], tt[gi + (j << 4)], sm);
          sm += __shfl_xor(sm, 1); sm += __shfl_xor(sm, 2);
          sm += __shfl_xor(sm, 4); sm += __shfl_xor(sm, 8);
          if (gi == 0) dred[g] = sm;
        }
        __syncthreads();                     // B3 (dots ready)
        const int e  = tid & 255;
        const int hh = tid >> 8;
        const float ak = A[k][e], zk = Z[k][e];
        const float ca = cas[k], cz = czs[k];
        for (int kp = k + 1 + hh; kp < KB; kp += 2) {
          const int gg = (kp - k - 1) << 1;
          const float ea = A[k][c0 + kp], ez = Z[k][c0 + kp];
          const float da = dred[gg], dz = dred[gg + 1];
          A[kp][e] = fmaf(ca * ea, ak, fmaf(cz * ez, zk, A[kp][e]));
          Y[kp][e] = fmaf(ca * da, ak, fmaf(cz * dz, zk, Y[kp][e]));
        }
      }
    }
    __syncthreads();                         // Z[15]/cas[15] ready for phase C
    // ---- phase C: W_base += sum_k ca a a^T + cz z z^T ----
    for (int k = 0; k < KB; k++) {
      const float ca = cas[k], cz = czs[k];
      const float pa0 = ca * A[k][r0], pa1 = ca * A[k][r1];
      const float pz0 = cz * Z[k][r0], pz1 = cz * Z[k][r1];
      const float4* ab = (const float4*)&A[k][cbase];
      const float4* zb = (const float4*)&Z[k][cbase];
#pragma unroll
      for (int k4 = 0; k4 < 16; k4++) {
        const float4 av = ab[k4];
        const float4 zv = zb[k4];
        w0[(k4<<2)+0] = fmaf(pa0, av.x, fmaf(pz0, zv.x, w0[(k4<<2)+0]));
        w0[(k4<<2)+1] = fmaf(pa0, av.y, fmaf(pz0, zv.y, w0[(k4<<2)+1]));
        w0[(k4<<2)+2] = fmaf(pa0, av.z, fmaf(pz0, zv.z, w0[(k4<<2)+2]));
        w0[(k4<<2)+3] = fmaf(pa0, av.w, fmaf(pz0, zv.w, w0[(k4<<2)+3]));
        w1[(k4<<2)+0] = fmaf(pa1, av.x, fmaf(pz1, zv.x, w1[(k4<<2)+0]));
        w1[(k4<<2)+1] = fmaf(pa1, av.y, fmaf(pz1, zv.y, w1[(k4<<2)+1]));
        w1[(k4<<2)+2] = fmaf(pa1, av.z, fmaf(pz1, zv.z, w1[(k4<<2)+2]));
        w1[(k4<<2)+3] = fmaf(pa1, av.w, fmaf(pz1, zv.w, w1[(k4<<2)+3]));
      }
    }
  }
}

// ============================================================================
extern "C" void kernel_launch(void* const* d_in, const int* in_sizes, int n_in,
                              void* d_out, int out_size, void* d_ws, size_t ws_size,
                              hipStream_t stream) {
  (void)in_sizes; (void)n_in; (void)out_size; (void)ws_size;
  const float* Theta = (const float*)d_in[0];
  const float* Winit = (const float*)d_in[1];
  const float* Wc    = (const float*)d_in[2];
  const float* bc    = (const float*)d_in[3];
  const float* A1    = (const float*)d_in[4];
  const float* b1    = (const float*)d_in[5];
  const float* A2    = (const float*)d_in[6];
  const float* b2    = (const float*)d_in[7];
  const float* A3    = (const float*)d_in[8];
  const float* b3    = (const float*)d_in[9];
  float* out = (float*)d_out;

  float* A1T = (float*)d_ws;             // 65536 floats
  float* A2T = A1T + P * P;
  float* gyb = A2T + P * P;
  float* WcT = gyb + P * P;              // 65536 floats (1 MB total ws)

  const int lds1 = (48 * 260 + 4 * 256 * 17) * sizeof(float);   // 119552
  const int lds2 = (64 * 260 + 4 * 256 * 17) * sizeof(float);   // 136192
  hipFuncSetAttribute((const void*)k_pass1,
                      hipFuncAttributeMaxDynamicSharedMemorySize, lds1);
  hipFuncSetAttribute((const void*)k_pass2,
                      hipFuncAttributeMaxDynamicSharedMemorySize, lds2);

  hipMemcpyAsync(out, Theta, (size_t)256 * P * P * sizeof(float),
                 hipMemcpyDeviceToDevice, stream);

  k_transpose<<<32, 256, 0, stream>>>(A1, A2, A1T, A2T);
  k_wct<<<256, 256, 0, stream>>>(Wc, WcT);
  k_pass1<<<256, 512, lds1, stream>>>(out, Wc, bc, WcT);
  k_mlp<<<4096, 256, 0, stream>>>(out, A1T, b1, A2T, b2, A3, b3, gyb);
  k_pass2<<<256, 512, lds2, stream>>>(out, Winit, gyb);
}